// Round 2
// baseline (202.282 us; speedup 1.0000x reference)
//
#include <hip/hip_runtime.h>

static constexpr int NB  = 4;     // batch
static constexpr int NN  = 4096;  // nodes
static constexpr int KIN = 256;   // in features
static constexpr int FO  = 128;   // out features
static constexpr int NCH = 32;    // prefix chunks per batch
static constexpr int CH  = NN / NCH;  // 128
static constexpr float SLOPE = 0.01f;

__device__ __forceinline__ float f4c(const float4& v, int kk) {
  switch (kk) { case 0: return v.x; case 1: return v.y; case 2: return v.z; default: return v.w; }
}

// ---------------- Kernel 1: feats = x @ W (f32) -----------------------------
// grid 512 x 256 thr. W staged in LDS in two 128-row K-phases (64 KiB each).
// Wave wv handles rows rowbase..rowbase+7; lane owns cols {2l, 2l+1}.
__global__ __launch_bounds__(256) void k1_gemm(const float* __restrict__ x,
                                               const float* __restrict__ W,
                                               float* __restrict__ feats) {
  __shared__ float Wl[128 * FO];  // 64 KiB
  const int t = threadIdx.x, wv = t >> 6, lane = t & 63;
  const int rowbase = blockIdx.x * 32 + wv * 8;
  float acc[8][2];
#pragma unroll
  for (int m = 0; m < 8; ++m) { acc[m][0] = 0.f; acc[m][1] = 0.f; }
  for (int ph = 0; ph < 2; ++ph) {
    __syncthreads();
    const float4* Wg = (const float4*)(W + ph * 128 * FO);
    float4* Ws = (float4*)Wl;
    for (int v = t; v < 128 * FO / 4; v += 256) Ws[v] = Wg[v];
    __syncthreads();
    const float* xb = x + ph * 128;
    for (int k = 0; k < 128; k += 4) {
      float4 xv[8];
#pragma unroll
      for (int m = 0; m < 8; ++m)
        xv[m] = *(const float4*)(xb + (rowbase + m) * KIN + k);
#pragma unroll
      for (int kk = 0; kk < 4; ++kk) {
        const float2 w = *(const float2*)(Wl + (k + kk) * FO + 2 * lane);
#pragma unroll
        for (int m = 0; m < 8; ++m) {
          const float xm = f4c(xv[m], kk);
          acc[m][0] = fmaf(xm, w.x, acc[m][0]);
          acc[m][1] = fmaf(xm, w.y, acc[m][1]);
        }
      }
    }
  }
#pragma unroll
  for (int m = 0; m < 8; ++m) {
    float2 r; r.x = acc[m][0]; r.y = acc[m][1];
    *(float2*)(feats + (rowbase + m) * FO + 2 * lane) = r;
  }
}

// ---------------- Kernel 2: f1/f2 + exp factors -----------------------------
// grid NB*NN/64 x 64 thr (1 wave, 64 rows serially).
__global__ __launch_bounds__(64) void k2_f12(const float* __restrict__ feats,
                                             const float* __restrict__ wl,
                                             const float* __restrict__ blp,
                                             const float* __restrict__ wr,
                                             const float* __restrict__ brp,
                                             float* __restrict__ f1g,
                                             float* __restrict__ f2g,
                                             float* __restrict__ E1g,
                                             float* __restrict__ E2g) {
  const int lane = threadIdx.x;
  const float2 wlv = *(const float2*)(wl + 2 * lane);
  const float2 wrv = *(const float2*)(wr + 2 * lane);
  const float bl = blp[0], br = brp[0];
  const int row0 = blockIdx.x * 64;
  for (int r = 0; r < 64; ++r) {
    const int row = row0 + r;
    const float2 v = *(const float2*)(feats + row * FO + 2 * lane);
    float a1 = v.x * wlv.x + v.y * wlv.y;
    float a2 = v.x * wrv.x + v.y * wrv.y;
    for (int off = 32; off; off >>= 1) {
      a1 += __shfl_down(a1, off);
      a2 += __shfl_down(a2, off);
    }
    if (lane == 0) {
      const float f1 = a1 + bl, f2 = a2 + br;
      f1g[row] = f1; f2g[row] = f2;
      E1g[row] = expf(f1); E2g[row] = expf(SLOPE * f1);
    }
  }
}

// ---------------- Kernel 3a: parallel sorts + scans -------------------------
// grid 8 x 1024. task 0 (blocks 0-3): sort f1 asc, write f1sort, scans sc1/sc2.
// task 1 (blocks 4-7): sort (f2, j) pairs asc, write f2sort + jidxS.
__global__ __launch_bounds__(1024, 1) void k3a_sort(const float* __restrict__ f1g,
                                                    const float* __restrict__ f2g,
                                                    float* __restrict__ f1sort,
                                                    float* __restrict__ sc1,
                                                    float* __restrict__ sc2,
                                                    float* __restrict__ f2sort,
                                                    int* __restrict__ jidxS) {
  __shared__ float key[NN];
  __shared__ float scr[NN];
  __shared__ int   idx[NN];
  const int tid = threadIdx.x;
  const int b = blockIdx.x & 3;
  const int task = blockIdx.x >> 2;
  const int base = b * NN;

  if (task == 0) {
    for (int i = tid; i < NN; i += 1024) key[i] = f1g[base + i];
    __syncthreads();
    for (int k = 2; k <= NN; k <<= 1) {
      for (int j = k >> 1; j > 0; j >>= 1) {
        for (int i = tid; i < NN; i += 1024) {
          const int ixj = i ^ j;
          if (ixj > i) {
            const float xv = key[i], yv = key[ixj];
            if ((xv > yv) == ((i & k) == 0)) { key[i] = yv; key[ixj] = xv; }
          }
        }
        __syncthreads();
      }
    }
    for (int i = tid; i < NN; i += 1024) f1sort[base + i] = key[i];
    // scan exp(key) -> sc1
    for (int i = tid; i < NN; i += 1024) scr[i] = expf(key[i]);
    __syncthreads();
    for (int d = 1; d < NN; d <<= 1) {
      float tv[4];
#pragma unroll
      for (int q = 0; q < 4; ++q) { const int i = tid + q * 1024; tv[q] = (i >= d) ? scr[i - d] : 0.f; }
      __syncthreads();
#pragma unroll
      for (int q = 0; q < 4; ++q) { const int i = tid + q * 1024; scr[i] += tv[q]; }
      __syncthreads();
    }
    for (int i = tid; i < NN; i += 1024) sc1[base + i] = scr[i];
    // scan exp(SLOPE*key) -> sc2
    for (int i = tid; i < NN; i += 1024) scr[i] = expf(SLOPE * key[i]);
    __syncthreads();
    for (int d = 1; d < NN; d <<= 1) {
      float tv[4];
#pragma unroll
      for (int q = 0; q < 4; ++q) { const int i = tid + q * 1024; tv[q] = (i >= d) ? scr[i - d] : 0.f; }
      __syncthreads();
#pragma unroll
      for (int q = 0; q < 4; ++q) { const int i = tid + q * 1024; scr[i] += tv[q]; }
      __syncthreads();
    }
    for (int i = tid; i < NN; i += 1024) sc2[base + i] = scr[i];
  } else {
    for (int i = tid; i < NN; i += 1024) { key[i] = f2g[base + i]; idx[i] = i; }
    __syncthreads();
    for (int k = 2; k <= NN; k <<= 1) {
      for (int j = k >> 1; j > 0; j >>= 1) {
        for (int i = tid; i < NN; i += 1024) {
          const int ixj = i ^ j;
          if (ixj > i) {
            const float xv = key[i], yv = key[ixj];
            if ((xv > yv) == ((i & k) == 0)) {
              const int xi = idx[i], yi = idx[ixj];
              key[i] = yv; key[ixj] = xv; idx[i] = yi; idx[ixj] = xi;
            }
          }
        }
        __syncthreads();
      }
    }
    for (int i = tid; i < NN; i += 1024) { f2sort[base + i] = key[i]; jidxS[base + i] = idx[i]; }
  }
}

// ---------------- Kernel 3b: alpha/beta per sorted-j, kpos per i ------------
// grid NB*8 x 512. Sorted arrays staged in LDS for binary search.
__device__ __forceinline__ int lower_bound_s(const float* a, int n, float t) {
  int lo = 0, hi = n;
  while (lo < hi) {
    const int mid = (lo + hi) >> 1;
    if (a[mid] < t) lo = mid + 1; else hi = mid;
  }
  return lo;
}

__global__ __launch_bounds__(512) void k3b_ab(const float* __restrict__ f1sort,
                                              const float* __restrict__ sc1,
                                              const float* __restrict__ sc2,
                                              const float* __restrict__ f2sort,
                                              const float* __restrict__ f1g,
                                              float* __restrict__ alphaS,
                                              float* __restrict__ betaS,
                                              int* __restrict__ kposA) {
  __shared__ float s_f1[NN];  // 16 KiB
  __shared__ float s_f2[NN];  // 16 KiB
  const int b = blockIdx.x >> 3;
  const int part = blockIdx.x & 7;
  const int base = b * NN;
  for (int i = threadIdx.x; i < NN; i += 512) {
    s_f1[i] = f1sort[base + i];
    s_f2[i] = f2sort[base + i];
  }
  __syncthreads();
  const int g = part * 512 + threadIdx.x;
  const float T1 = sc1[base + NN - 1];
  const float f1max = s_f1[NN - 1];
  {
    const float f2v = s_f2[g];
    const float m = f1max + f2v;
    const float M = (m >= 0.f) ? m : SLOPE * m;      // column max of leaky scores
    const int p = lower_bound_s(s_f1, NN, -f2v);     // first i with f1 >= -f2
    const float S1 = T1 - (p > 0 ? sc1[base + p - 1] : 0.f);
    const float S2 = (p > 0 ? sc2[base + p - 1] : 0.f);
    const float ea = expf(f2v - M);
    const float eb = expf(SLOPE * f2v - M);
    const float invD = 1.0f / (ea * S1 + eb * S2);
    alphaS[base + g] = ea * invD;
    betaS[base + g]  = eb * invD;
  }
  {
    const float f1v = f1g[base + g];
    kposA[base + g] = lower_bound_s(s_f2, NN, -f1v); // first sorted-j with f2 >= -f1
  }
}

// ---------------- Kernel 4a: per-chunk partial sums -------------------------
__global__ __launch_bounds__(128) void k4a_csum(const float* __restrict__ feats,
                                                const float* __restrict__ alphaS,
                                                const float* __restrict__ betaS,
                                                const int* __restrict__ jidxS,
                                                float* __restrict__ csumA,
                                                float* __restrict__ csumB) {
  const int b = blockIdx.x / NCH, c = blockIdx.x % NCH;
  const int o = threadIdx.x;
  const int base = b * NN + c * CH;
  const float* fb = feats + b * NN * FO;
  float accA = 0.f, accB = 0.f;
#pragma unroll 4
  for (int q = 0; q < CH; ++q) {
    const int kk = base + q;
    const int j = jidxS[kk];
    const float fv = fb[j * FO + o];
    accA = fmaf(alphaS[kk], fv, accA);
    accB = fmaf(betaS[kk], fv, accB);
  }
  csumA[(b * NCH + c) * FO + o] = accA;
  csumB[(b * NCH + c) * FO + o] = accB;
}

// ---------------- Kernel 4b: exclusive prefix arrays ------------------------
__global__ __launch_bounds__(128) void k4b_prefix(const float* __restrict__ feats,
                                                  const float* __restrict__ alphaS,
                                                  const float* __restrict__ betaS,
                                                  const int* __restrict__ jidxS,
                                                  const float* __restrict__ csumA,
                                                  const float* __restrict__ csumB,
                                                  float* __restrict__ prefA,
                                                  float* __restrict__ prefB) {
  const int b = blockIdx.x / NCH, c = blockIdx.x % NCH;
  const int o = threadIdx.x;
  float runA = 0.f, runB = 0.f;
  for (int c2 = 0; c2 < c; ++c2) {
    runA += csumA[(b * NCH + c2) * FO + o];
    runB += csumB[(b * NCH + c2) * FO + o];
  }
  const int base = b * NN + c * CH;
  const float* fb = feats + b * NN * FO;
  float* pA = prefA + (size_t)(b * (NN + 1) + c * CH) * FO + o;
  float* pB = prefB + (size_t)(b * (NN + 1) + c * CH) * FO + o;
  for (int q = 0; q < CH; ++q) {
    pA[q * FO] = runA;
    pB[q * FO] = runB;
    const int kk = base + q;
    const int j = jidxS[kk];
    const float fv = fb[j * FO + o];
    runA = fmaf(alphaS[kk], fv, runA);
    runB = fmaf(betaS[kk], fv, runB);
  }
  if (c == NCH - 1) {
    prefA[(size_t)(b * (NN + 1) + NN) * FO + o] = runA;
    prefB[(size_t)(b * (NN + 1) + NN) * FO + o] = runB;
  }
}

// ---------------- Kernel 5: epilogue combine (f32 out) ----------------------
// out[i,:] = E1_i * (totalA - prefA[k_i]) + E2_i * prefB[k_i]
__global__ __launch_bounds__(256) void k5_out(const float* __restrict__ prefA,
                                              const float* __restrict__ prefB,
                                              const int* __restrict__ kposA,
                                              const float* __restrict__ E1g,
                                              const float* __restrict__ E2g,
                                              float* __restrict__ out) {
  const int t = threadIdx.x;
  const int row = blockIdx.x * 2 + (t >> 7);
  const int o = t & 127;
  const int b = row >> 12;  // NN = 4096
  const int kp = kposA[row];
  const float e1 = E1g[row], e2 = E2g[row];
  const float* pAb = prefA + (size_t)(b * (NN + 1)) * FO;
  const float* pBb = prefB + (size_t)(b * (NN + 1)) * FO;
  const float totA = pAb[(size_t)NN * FO + o];
  const float pA = pAb[(size_t)kp * FO + o];
  const float pB = pBb[(size_t)kp * FO + o];
  out[(size_t)row * FO + o] = fmaf(e1, totA - pA, e2 * pB);
}

extern "C" void kernel_launch(void* const* d_in, const int* in_sizes, int n_in,
                              void* d_out, int out_size, void* d_ws, size_t ws_size,
                              hipStream_t stream) {
  const float* x  = (const float*)d_in[0];
  const float* W  = (const float*)d_in[1];
  const float* wl = (const float*)d_in[2];
  const float* bl = (const float*)d_in[3];
  const float* wr = (const float*)d_in[4];
  const float* br = (const float*)d_in[5];
  float* out = (float*)d_out;

  float* ws = (float*)d_ws;
  float* feats  = ws; ws += NB * NN * FO;
  float* f1g    = ws; ws += NB * NN;
  float* f2g    = ws; ws += NB * NN;
  float* f1sort = ws; ws += NB * NN;
  float* f2sort = ws; ws += NB * NN;
  float* sc1    = ws; ws += NB * NN;
  float* sc2    = ws; ws += NB * NN;
  float* alphaS = ws; ws += NB * NN;
  float* betaS  = ws; ws += NB * NN;
  float* E1g    = ws; ws += NB * NN;
  float* E2g    = ws; ws += NB * NN;
  int* jidxS    = (int*)ws; ws += NB * NN;
  int* kposA    = (int*)ws; ws += NB * NN;
  float* csumA  = ws; ws += NB * NCH * FO;
  float* csumB  = ws; ws += NB * NCH * FO;
  float* prefA  = ws; ws += NB * (NN + 1) * FO;
  float* prefB  = ws; ws += NB * (NN + 1) * FO;
  (void)in_sizes; (void)n_in; (void)out_size; (void)ws_size;

  hipLaunchKernelGGL(k1_gemm,   dim3(NB * NN / 32), dim3(256),  0, stream, x, W, feats);
  hipLaunchKernelGGL(k2_f12,    dim3(NB * NN / 64), dim3(64),   0, stream, feats, wl, bl, wr, br, f1g, f2g, E1g, E2g);
  hipLaunchKernelGGL(k3a_sort,  dim3(8),            dim3(1024), 0, stream, f1g, f2g, f1sort, sc1, sc2, f2sort, jidxS);
  hipLaunchKernelGGL(k3b_ab,    dim3(NB * 8),       dim3(512),  0, stream, f1sort, sc1, sc2, f2sort, f1g, alphaS, betaS, kposA);
  hipLaunchKernelGGL(k4a_csum,  dim3(NB * NCH),     dim3(128),  0, stream, feats, alphaS, betaS, jidxS, csumA, csumB);
  hipLaunchKernelGGL(k4b_prefix,dim3(NB * NCH),     dim3(128),  0, stream, feats, alphaS, betaS, jidxS, csumA, csumB, prefA, prefB);
  hipLaunchKernelGGL(k5_out,    dim3(NB * NN / 2),  dim3(256),  0, stream, prefA, prefB, kposA, E1g, E2g, out);
}

// Round 3
// 115.477 us; speedup vs baseline: 1.7517x; 1.7517x over previous
//
#include <hip/hip_runtime.h>

using u32 = unsigned int;
using u64 = unsigned long long;

static constexpr int NB  = 4;     // batch
static constexpr int NN  = 4096;  // nodes
static constexpr int KIN = 256;   // in features
static constexpr int FO  = 128;   // out features
static constexpr int NCH = 32;    // prefix chunks per batch
static constexpr int CH  = NN / NCH;  // 128
static constexpr float SLOPE = 0.01f;

__device__ __forceinline__ float f4c(const float4& v, int kk) {
  switch (kk) { case 0: return v.x; case 1: return v.y; case 2: return v.z; default: return v.w; }
}

// monotone bijection f32 -> orderable u32 (no NaNs present)
__device__ __forceinline__ u32 f2key(float f) {
  const u32 b = __float_as_uint(f);
  return (b & 0x80000000u) ? ~b : (b | 0x80000000u);
}
__device__ __forceinline__ float key2f(u32 u) {
  const u32 b = (u & 0x80000000u) ? (u ^ 0x80000000u) : ~u;
  return __uint_as_float(b);
}

__device__ __forceinline__ u64 shfl_xor64(u64 v, int m) {
  const u32 lo = __shfl_xor((u32)(v & 0xffffffffu), m, 64);
  const u32 hi = __shfl_xor((u32)(v >> 32), m, 64);
  return ((u64)hi << 32) | (u64)lo;
}
__device__ __forceinline__ void cswap(u64& a, u64& b, bool up) {
  if ((a > b) == up) { const u64 tmp = a; a = b; b = tmp; }
}

// bitonic rounds j = min(k/2,128)..1 for phase k, data in registers.
// thread t holds elements i = 4t+r. Valid for any k >= 2.
__device__ __forceinline__ void reg_session(u64 e[4], int t, int k) {
  const int jstart = (k > 256) ? 128 : (k >> 1);
  for (int j = jstart; j >= 4; j >>= 1) {
    const int J = j >> 2;
    const bool up   = ((t & (k >> 2)) == 0);
    const bool lowr = ((t & J) == 0);
#pragma unroll
    for (int r = 0; r < 4; ++r) {
      const u64 o = shfl_xor64(e[r], J);
      const bool less = e[r] < o;              // keys unique (idx tie-break)
      e[r] = ((lowr == up) == less) ? e[r] : o;
    }
  }
  if (k >= 4) {
    const bool up = ((t & (k >> 2)) == 0);
    cswap(e[0], e[2], up); cswap(e[1], e[3], up);
  }
  {
    const bool up0 = (((4 * t)     & k) == 0);
    const bool up1 = (((4 * t + 2) & k) == 0);
    cswap(e[0], e[1], up0); cswap(e[2], e[3], up1);
  }
}

// ---------------- Kernel 1: feats = x @ W, fused f1/f2/E1/E2 ---------------
// grid 512 x 256 thr. W staged in LDS in two 128-row K-phases (64 KiB).
__global__ __launch_bounds__(256) void k1_gemm(const float* __restrict__ x,
                                               const float* __restrict__ W,
                                               const float* __restrict__ wl,
                                               const float* __restrict__ blp,
                                               const float* __restrict__ wr,
                                               const float* __restrict__ brp,
                                               float* __restrict__ feats,
                                               float* __restrict__ f1g,
                                               float* __restrict__ f2g,
                                               float* __restrict__ E1g,
                                               float* __restrict__ E2g) {
  __shared__ float Wl[128 * FO];  // 64 KiB
  const int t = threadIdx.x, wv = t >> 6, lane = t & 63;
  const int rowbase = blockIdx.x * 32 + wv * 8;
  const float2 wlv = *(const float2*)(wl + 2 * lane);
  const float2 wrv = *(const float2*)(wr + 2 * lane);
  const float bl = blp[0], br = brp[0];
  float acc[8][2];
#pragma unroll
  for (int m = 0; m < 8; ++m) { acc[m][0] = 0.f; acc[m][1] = 0.f; }
  for (int ph = 0; ph < 2; ++ph) {
    __syncthreads();
    const float4* Wg = (const float4*)(W + ph * 128 * FO);
    float4* Ws = (float4*)Wl;
    for (int v = t; v < 128 * FO / 4; v += 256) Ws[v] = Wg[v];
    __syncthreads();
    const float* xb = x + ph * 128;
    for (int k = 0; k < 128; k += 4) {
      float4 xv[8];
#pragma unroll
      for (int m = 0; m < 8; ++m)
        xv[m] = *(const float4*)(xb + (rowbase + m) * KIN + k);
#pragma unroll
      for (int kk = 0; kk < 4; ++kk) {
        const float2 w = *(const float2*)(Wl + (k + kk) * FO + 2 * lane);
#pragma unroll
        for (int m = 0; m < 8; ++m) {
          const float xm = f4c(xv[m], kk);
          acc[m][0] = fmaf(xm, w.x, acc[m][0]);
          acc[m][1] = fmaf(xm, w.y, acc[m][1]);
        }
      }
    }
  }
#pragma unroll
  for (int m = 0; m < 8; ++m) {
    const int row = rowbase + m;
    float2 r; r.x = acc[m][0]; r.y = acc[m][1];
    *(float2*)(feats + row * FO + 2 * lane) = r;
    float d1 = acc[m][0] * wlv.x + acc[m][1] * wlv.y;
    float d2 = acc[m][0] * wrv.x + acc[m][1] * wrv.y;
    for (int off = 32; off; off >>= 1) {
      d1 += __shfl_down(d1, off, 64);
      d2 += __shfl_down(d2, off, 64);
    }
    if (lane == 0) {
      const float f1 = d1 + bl, f2v = d2 + br;
      f1g[row] = f1; f2g[row] = f2v;
      E1g[row] = expf(f1); E2g[row] = expf(SLOPE * f1);
    }
  }
}

// ---------------- Kernel 3a: hierarchical bitonic sorts + scans -------------
// grid 8 x 1024. task 0 (blocks 0-3): sort f1 asc -> f1sort + dual exp scans.
// task 1 (blocks 4-7): sort (f2, j) -> f2sort + jidxS.
__global__ __launch_bounds__(1024, 1) void k3a_sort(const float* __restrict__ f1g,
                                                    const float* __restrict__ f2g,
                                                    float* __restrict__ f1sort,
                                                    float* __restrict__ sc1,
                                                    float* __restrict__ sc2,
                                                    float* __restrict__ f2sort,
                                                    int* __restrict__ jidxS) {
  __shared__ u64 lds[NN];          // 32 KiB
  __shared__ float wsumA[16], wsumB[16];
  const int t = threadIdx.x;
  const int lane = t & 63, wv = t >> 6;
  const int b = blockIdx.x & 3;
  const int task = blockIdx.x >> 2;
  const int base = b * NN;
  const float* __restrict__ src = task ? f2g : f1g;

  u64 e[4];
#pragma unroll
  for (int r = 0; r < 4; ++r) {
    const int i = 4 * t + r;
    e[r] = ((u64)f2key(src[base + i]) << 32) | (u32)i;
  }

  // phases k = 2..256 entirely in registers/shuffles
  for (int k = 2; k <= 256; k <<= 1) reg_session(e, t, k);
#pragma unroll
  for (int r = 0; r < 4; ++r) lds[4 * t + r] = e[r];
  __syncthreads();

  // phases k = 512..4096: LDS rounds for j>=256, register tail for j<=128
  for (int k = 512; k <= NN; k <<= 1) {
    for (int j = k >> 1; j >= 256; j >>= 1) {
#pragma unroll
      for (int pp = 0; pp < 2; ++pp) {
        const int p = t + pp * 1024;
        const int i = ((p & ~(j - 1)) << 1) | (p & (j - 1));
        const int ix = i | j;
        const bool up = ((i & k) == 0);
        const u64 a = lds[i], c = lds[ix];
        if ((a > c) == up) { lds[i] = c; lds[ix] = a; }
      }
      __syncthreads();
    }
#pragma unroll
    for (int r = 0; r < 4; ++r) e[r] = lds[4 * t + r];
    reg_session(e, t, k);
    if (k < NN) {
#pragma unroll
      for (int r = 0; r < 4; ++r) lds[4 * t + r] = e[r];
      __syncthreads();
    }
  }
  // e[] now globally sorted ascending; thread t holds ranks 4t..4t+3.

  if (task == 0) {
    float kf[4], a[4], c[4];
#pragma unroll
    for (int r = 0; r < 4; ++r) {
      kf[r] = key2f((u32)(e[r] >> 32));
      f1sort[base + 4 * t + r] = kf[r];
      a[r] = expf(kf[r]);
      c[r] = expf(SLOPE * kf[r]);
    }
#pragma unroll
    for (int r = 1; r < 4; ++r) { a[r] += a[r - 1]; c[r] += c[r - 1]; }
    const float sa = a[3], sb = c[3];
    float pa = sa, pb = sb;
    for (int off = 1; off < 64; off <<= 1) {
      const float oa = __shfl_up(pa, off, 64);
      const float ob = __shfl_up(pb, off, 64);
      if (lane >= off) { pa += oa; pb += ob; }
    }
    if (lane == 63) { wsumA[wv] = pa; wsumB[wv] = pb; }
    __syncthreads();
    float wpa = 0.f, wpb = 0.f;
    for (int w2 = 0; w2 < wv; ++w2) { wpa += wsumA[w2]; wpb += wsumB[w2]; }
    const float basea = wpa + pa - sa, baseb = wpb + pb - sb;
#pragma unroll
    for (int r = 0; r < 4; ++r) {
      sc1[base + 4 * t + r] = basea + a[r];
      sc2[base + 4 * t + r] = baseb + c[r];
    }
  } else {
#pragma unroll
    for (int r = 0; r < 4; ++r) {
      f2sort[base + 4 * t + r] = key2f((u32)(e[r] >> 32));
      jidxS[base + 4 * t + r]  = (int)(e[r] & 0xffffffffu);
    }
  }
}

// ---------------- Kernel 3b: alpha/beta per sorted-j, kpos per i ------------
__device__ __forceinline__ int lower_bound_s(const float* a, int n, float t) {
  int lo = 0, hi = n;
  while (lo < hi) {
    const int mid = (lo + hi) >> 1;
    if (a[mid] < t) lo = mid + 1; else hi = mid;
  }
  return lo;
}

__global__ __launch_bounds__(512) void k3b_ab(const float* __restrict__ f1sort,
                                              const float* __restrict__ sc1,
                                              const float* __restrict__ sc2,
                                              const float* __restrict__ f2sort,
                                              const float* __restrict__ f1g,
                                              float* __restrict__ alphaS,
                                              float* __restrict__ betaS,
                                              int* __restrict__ kposA) {
  __shared__ float s_f1[NN];  // 16 KiB
  __shared__ float s_f2[NN];  // 16 KiB
  const int b = blockIdx.x >> 3;
  const int part = blockIdx.x & 7;
  const int base = b * NN;
  for (int i = threadIdx.x; i < NN; i += 512) {
    s_f1[i] = f1sort[base + i];
    s_f2[i] = f2sort[base + i];
  }
  __syncthreads();
  const int g = part * 512 + threadIdx.x;
  const float T1 = sc1[base + NN - 1];
  const float f1max = s_f1[NN - 1];
  {
    const float f2v = s_f2[g];
    const float m = f1max + f2v;
    const float M = (m >= 0.f) ? m : SLOPE * m;      // column max of leaky scores
    const int p = lower_bound_s(s_f1, NN, -f2v);     // first i with f1 >= -f2
    const float S1 = T1 - (p > 0 ? sc1[base + p - 1] : 0.f);
    const float S2 = (p > 0 ? sc2[base + p - 1] : 0.f);
    const float ea = expf(f2v - M);
    const float eb = expf(SLOPE * f2v - M);
    const float invD = 1.0f / (ea * S1 + eb * S2);
    alphaS[base + g] = ea * invD;
    betaS[base + g]  = eb * invD;
  }
  {
    const float f1v = f1g[base + g];
    kposA[base + g] = lower_bound_s(s_f2, NN, -f1v); // first sorted-j with f2 >= -f1
  }
}

// ---------------- Kernel 4a: per-chunk partial sums -------------------------
__global__ __launch_bounds__(128) void k4a_csum(const float* __restrict__ feats,
                                                const float* __restrict__ alphaS,
                                                const float* __restrict__ betaS,
                                                const int* __restrict__ jidxS,
                                                float* __restrict__ csumA,
                                                float* __restrict__ csumB) {
  const int b = blockIdx.x / NCH, c = blockIdx.x % NCH;
  const int o = threadIdx.x;
  const int base = b * NN + c * CH;
  const float* fb = feats + b * NN * FO;
  float accA = 0.f, accB = 0.f;
#pragma unroll 4
  for (int q = 0; q < CH; ++q) {
    const int kk = base + q;
    const int j = jidxS[kk];
    const float fv = fb[j * FO + o];
    accA = fmaf(alphaS[kk], fv, accA);
    accB = fmaf(betaS[kk], fv, accB);
  }
  csumA[(b * NCH + c) * FO + o] = accA;
  csumB[(b * NCH + c) * FO + o] = accB;
}

// ---------------- Kernel 4b: exclusive prefix arrays ------------------------
__global__ __launch_bounds__(128) void k4b_prefix(const float* __restrict__ feats,
                                                  const float* __restrict__ alphaS,
                                                  const float* __restrict__ betaS,
                                                  const int* __restrict__ jidxS,
                                                  const float* __restrict__ csumA,
                                                  const float* __restrict__ csumB,
                                                  float* __restrict__ prefA,
                                                  float* __restrict__ prefB) {
  const int b = blockIdx.x / NCH, c = blockIdx.x % NCH;
  const int o = threadIdx.x;
  float runA = 0.f, runB = 0.f;
  for (int c2 = 0; c2 < c; ++c2) {
    runA += csumA[(b * NCH + c2) * FO + o];
    runB += csumB[(b * NCH + c2) * FO + o];
  }
  const int base = b * NN + c * CH;
  const float* fb = feats + b * NN * FO;
  float* pA = prefA + (size_t)(b * (NN + 1) + c * CH) * FO + o;
  float* pB = prefB + (size_t)(b * (NN + 1) + c * CH) * FO + o;
  for (int q = 0; q < CH; ++q) {
    pA[q * FO] = runA;
    pB[q * FO] = runB;
    const int kk = base + q;
    const int j = jidxS[kk];
    const float fv = fb[j * FO + o];
    runA = fmaf(alphaS[kk], fv, runA);
    runB = fmaf(betaS[kk], fv, runB);
  }
  if (c == NCH - 1) {
    prefA[(size_t)(b * (NN + 1) + NN) * FO + o] = runA;
    prefB[(size_t)(b * (NN + 1) + NN) * FO + o] = runB;
  }
}

// ---------------- Kernel 5: epilogue combine (f32 out) ----------------------
__global__ __launch_bounds__(256) void k5_out(const float* __restrict__ prefA,
                                              const float* __restrict__ prefB,
                                              const int* __restrict__ kposA,
                                              const float* __restrict__ E1g,
                                              const float* __restrict__ E2g,
                                              float* __restrict__ out) {
  const int t = threadIdx.x;
  const int row = blockIdx.x * 2 + (t >> 7);
  const int o = t & 127;
  const int b = row >> 12;  // NN = 4096
  const int kp = kposA[row];
  const float e1 = E1g[row], e2 = E2g[row];
  const float* pAb = prefA + (size_t)(b * (NN + 1)) * FO;
  const float* pBb = prefB + (size_t)(b * (NN + 1)) * FO;
  const float totA = pAb[(size_t)NN * FO + o];
  const float pA = pAb[(size_t)kp * FO + o];
  const float pB = pBb[(size_t)kp * FO + o];
  out[(size_t)row * FO + o] = fmaf(e1, totA - pA, e2 * pB);
}

extern "C" void kernel_launch(void* const* d_in, const int* in_sizes, int n_in,
                              void* d_out, int out_size, void* d_ws, size_t ws_size,
                              hipStream_t stream) {
  const float* x  = (const float*)d_in[0];
  const float* W  = (const float*)d_in[1];
  const float* wl = (const float*)d_in[2];
  const float* bl = (const float*)d_in[3];
  const float* wr = (const float*)d_in[4];
  const float* br = (const float*)d_in[5];
  float* out = (float*)d_out;

  float* ws = (float*)d_ws;
  float* feats  = ws; ws += NB * NN * FO;
  float* f1g    = ws; ws += NB * NN;
  float* f2g    = ws; ws += NB * NN;
  float* f1sort = ws; ws += NB * NN;
  float* f2sort = ws; ws += NB * NN;
  float* sc1    = ws; ws += NB * NN;
  float* sc2    = ws; ws += NB * NN;
  float* alphaS = ws; ws += NB * NN;
  float* betaS  = ws; ws += NB * NN;
  float* E1g    = ws; ws += NB * NN;
  float* E2g    = ws; ws += NB * NN;
  int* jidxS    = (int*)ws; ws += NB * NN;
  int* kposA    = (int*)ws; ws += NB * NN;
  float* csumA  = ws; ws += NB * NCH * FO;
  float* csumB  = ws; ws += NB * NCH * FO;
  float* prefA  = ws; ws += NB * (NN + 1) * FO;
  float* prefB  = ws; ws += NB * (NN + 1) * FO;
  (void)in_sizes; (void)n_in; (void)out_size; (void)ws_size;

  hipLaunchKernelGGL(k1_gemm,   dim3(NB * NN / 32), dim3(256),  0, stream,
                     x, W, wl, bl, wr, br, feats, f1g, f2g, E1g, E2g);
  hipLaunchKernelGGL(k3a_sort,  dim3(8),            dim3(1024), 0, stream,
                     f1g, f2g, f1sort, sc1, sc2, f2sort, jidxS);
  hipLaunchKernelGGL(k3b_ab,    dim3(NB * 8),       dim3(512),  0, stream,
                     f1sort, sc1, sc2, f2sort, f1g, alphaS, betaS, kposA);
  hipLaunchKernelGGL(k4a_csum,  dim3(NB * NCH),     dim3(128),  0, stream,
                     feats, alphaS, betaS, jidxS, csumA, csumB);
  hipLaunchKernelGGL(k4b_prefix,dim3(NB * NCH),     dim3(128),  0, stream,
                     feats, alphaS, betaS, jidxS, csumA, csumB, prefA, prefB);
  hipLaunchKernelGGL(k5_out,    dim3(NB * NN / 2),  dim3(256),  0, stream,
                     prefA, prefB, kposA, E1g, E2g, out);
}

// Round 4
// 89.901 us; speedup vs baseline: 2.2501x; 1.2845x over previous
//
#include <hip/hip_runtime.h>

using u32 = unsigned int;
using u64 = unsigned long long;

static constexpr int NB  = 4;     // batch
static constexpr int NN  = 4096;  // nodes
static constexpr int KIN = 256;   // in features
static constexpr int FO  = 128;   // out features
static constexpr int NCH = 64;    // prefix chunks per batch
static constexpr int CH  = NN / NCH;  // 64
static constexpr float SLOPE = 0.01f;

__device__ __forceinline__ float f4c(const float4& v, int kk) {
  switch (kk) { case 0: return v.x; case 1: return v.y; case 2: return v.z; default: return v.w; }
}

// monotone bijection f32 -> orderable u32 (no NaNs present)
__device__ __forceinline__ u32 f2key(float f) {
  const u32 b = __float_as_uint(f);
  return (b & 0x80000000u) ? ~b : (b | 0x80000000u);
}
__device__ __forceinline__ float key2f(u32 u) {
  const u32 b = (u & 0x80000000u) ? (u ^ 0x80000000u) : ~u;
  return __uint_as_float(b);
}

__device__ __forceinline__ u64 shfl_xor64(u64 v, int m) {
  const u32 lo = __shfl_xor((u32)(v & 0xffffffffu), m, 64);
  const u32 hi = __shfl_xor((u32)(v >> 32), m, 64);
  return ((u64)hi << 32) | (u64)lo;
}
__device__ __forceinline__ void cswap(u64& a, u64& b, bool up) {
  if ((a > b) == up) { const u64 tmp = a; a = b; b = tmp; }
}

// bitonic rounds j = min(k/2,128)..1 for phase k, data in registers.
// thread t holds elements i = 4t+r. Valid for any k >= 2.
__device__ __forceinline__ void reg_session(u64 e[4], int t, int k) {
  const int jstart = (k > 256) ? 128 : (k >> 1);
  for (int j = jstart; j >= 4; j >>= 1) {
    const int J = j >> 2;
    const bool up   = ((t & (k >> 2)) == 0);
    const bool lowr = ((t & J) == 0);
#pragma unroll
    for (int r = 0; r < 4; ++r) {
      const u64 o = shfl_xor64(e[r], J);
      const bool less = e[r] < o;              // keys unique (idx tie-break)
      e[r] = ((lowr == up) == less) ? e[r] : o;
    }
  }
  if (k >= 4) {
    const bool up = ((t & (k >> 2)) == 0);
    cswap(e[0], e[2], up); cswap(e[1], e[3], up);
  }
  {
    const bool up0 = (((4 * t)     & k) == 0);
    const bool up1 = (((4 * t + 2) & k) == 0);
    cswap(e[0], e[1], up0); cswap(e[2], e[3], up1);
  }
}

// ---------------- Kernel 1: feats = x @ W, fused f1/f2/E1/E2 ---------------
// grid 512 x 256 thr. Tile M=32 x FO=128; per-thread 4x4 register block.
// K in 4 phases of 64: xs (8.5 KB) + ws (32 KB) staged coalesced in LDS.
__global__ __launch_bounds__(256) void k1_gemm(const float* __restrict__ x,
                                               const float* __restrict__ W,
                                               const float* __restrict__ wl,
                                               const float* __restrict__ blp,
                                               const float* __restrict__ wr,
                                               const float* __restrict__ brp,
                                               float* __restrict__ feats,
                                               float* __restrict__ f1g,
                                               float* __restrict__ f2g,
                                               float* __restrict__ E1g,
                                               float* __restrict__ E2g) {
  __shared__ float xs[32][68];    // 32 rows x 64 k (padded)
  __shared__ float wsd[64][128];  // k x col
  const int t = threadIdx.x;
  const int rg = t >> 5;          // 0..7  (row group of 4)
  const int cg = t & 31;          // 0..31 (col group of 4)
  const int row0 = blockIdx.x * 32;
  float acc[4][4];
#pragma unroll
  for (int m = 0; m < 4; ++m)
#pragma unroll
    for (int n = 0; n < 4; ++n) acc[m][n] = 0.f;

  for (int ph = 0; ph < 4; ++ph) {
    __syncthreads();
    // stage W chunk: 64x128 = 2048 float4, contiguous
    const float4* Wg = (const float4*)(W + ph * 64 * FO);
#pragma unroll
    for (int i = 0; i < 8; ++i) {
      const int v = t + i * 256;
      *(float4*)(&wsd[v >> 5][(v & 31) * 4]) = Wg[v];
    }
    // stage x chunk: 32 rows x 64 k = 512 float4
#pragma unroll
    for (int i = 0; i < 2; ++i) {
      const int v = t + i * 256;
      const int r = v >> 4, c4 = (v & 15) * 4;
      *(float4*)(&xs[r][c4]) = *(const float4*)(x + (size_t)(row0 + r) * KIN + ph * 64 + c4);
    }
    __syncthreads();
    for (int k = 0; k < 64; k += 4) {
      float4 xv[4];
#pragma unroll
      for (int m = 0; m < 4; ++m) xv[m] = *(const float4*)(&xs[rg * 4 + m][k]);
#pragma unroll
      for (int kk = 0; kk < 4; ++kk) {
        const float4 wv = *(const float4*)(&wsd[k + kk][cg * 4]);
#pragma unroll
        for (int m = 0; m < 4; ++m) {
          const float xm = f4c(xv[m], kk);
          acc[m][0] = fmaf(xm, wv.x, acc[m][0]);
          acc[m][1] = fmaf(xm, wv.y, acc[m][1]);
          acc[m][2] = fmaf(xm, wv.z, acc[m][2]);
          acc[m][3] = fmaf(xm, wv.w, acc[m][3]);
        }
      }
    }
  }

  // write feats (float4 per row)
#pragma unroll
  for (int m = 0; m < 4; ++m) {
    float4 r; r.x = acc[m][0]; r.y = acc[m][1]; r.z = acc[m][2]; r.w = acc[m][3];
    *(float4*)(feats + (size_t)(row0 + rg * 4 + m) * FO + cg * 4) = r;
  }

  // fused f1/f2/E1/E2: reduce per-thread 4-col dots over the 32-lane cg group
  const float4 wlv = *(const float4*)(wl + cg * 4);
  const float4 wrv = *(const float4*)(wr + cg * 4);
  const float bl = blp[0], br = brp[0];
#pragma unroll
  for (int m = 0; m < 4; ++m) {
    float d1 = acc[m][0] * wlv.x + acc[m][1] * wlv.y + acc[m][2] * wlv.z + acc[m][3] * wlv.w;
    float d2 = acc[m][0] * wrv.x + acc[m][1] * wrv.y + acc[m][2] * wrv.z + acc[m][3] * wrv.w;
#pragma unroll
    for (int off = 1; off < 32; off <<= 1) {
      d1 += __shfl_xor(d1, off, 64);
      d2 += __shfl_xor(d2, off, 64);
    }
    if (cg == 0) {
      const int row = row0 + rg * 4 + m;
      const float f1 = d1 + bl, f2v = d2 + br;
      f1g[row] = f1; f2g[row] = f2v;
      E1g[row] = expf(f1); E2g[row] = expf(SLOPE * f1);
    }
  }
}

// ---------------- Kernel 3a: hierarchical bitonic sorts + scans -------------
// grid 8 x 1024. task 0 (blocks 0-3): sort f1 asc -> f1sort + dual exp scans.
// task 1 (blocks 4-7): sort (f2, j) -> f2sort + jidxS.
__global__ __launch_bounds__(1024, 1) void k3a_sort(const float* __restrict__ f1g,
                                                    const float* __restrict__ f2g,
                                                    float* __restrict__ f1sort,
                                                    float* __restrict__ sc1,
                                                    float* __restrict__ sc2,
                                                    float* __restrict__ f2sort,
                                                    int* __restrict__ jidxS) {
  __shared__ u64 lds[NN];          // 32 KiB
  __shared__ float wsumA[16], wsumB[16];
  const int t = threadIdx.x;
  const int lane = t & 63, wv = t >> 6;
  const int b = blockIdx.x & 3;
  const int task = blockIdx.x >> 2;
  const int base = b * NN;
  const float* __restrict__ src = task ? f2g : f1g;

  u64 e[4];
#pragma unroll
  for (int r = 0; r < 4; ++r) {
    const int i = 4 * t + r;
    e[r] = ((u64)f2key(src[base + i]) << 32) | (u32)i;
  }

  // phases k = 2..256 entirely in registers/shuffles
  for (int k = 2; k <= 256; k <<= 1) reg_session(e, t, k);
#pragma unroll
  for (int r = 0; r < 4; ++r) lds[4 * t + r] = e[r];
  __syncthreads();

  // phases k = 512..4096: LDS rounds for j>=256, register tail for j<=128
  for (int k = 512; k <= NN; k <<= 1) {
    for (int j = k >> 1; j >= 256; j >>= 1) {
#pragma unroll
      for (int pp = 0; pp < 2; ++pp) {
        const int p = t + pp * 1024;
        const int i = ((p & ~(j - 1)) << 1) | (p & (j - 1));
        const int ix = i | j;
        const bool up = ((i & k) == 0);
        const u64 a = lds[i], c = lds[ix];
        if ((a > c) == up) { lds[i] = c; lds[ix] = a; }
      }
      __syncthreads();
    }
#pragma unroll
    for (int r = 0; r < 4; ++r) e[r] = lds[4 * t + r];
    reg_session(e, t, k);
    if (k < NN) {
#pragma unroll
      for (int r = 0; r < 4; ++r) lds[4 * t + r] = e[r];
      __syncthreads();
    }
  }
  // e[] now globally sorted ascending; thread t holds ranks 4t..4t+3.

  if (task == 0) {
    float kf[4], a[4], c[4];
#pragma unroll
    for (int r = 0; r < 4; ++r) {
      kf[r] = key2f((u32)(e[r] >> 32));
      f1sort[base + 4 * t + r] = kf[r];
      a[r] = expf(kf[r]);
      c[r] = expf(SLOPE * kf[r]);
    }
#pragma unroll
    for (int r = 1; r < 4; ++r) { a[r] += a[r - 1]; c[r] += c[r - 1]; }
    const float sa = a[3], sb = c[3];
    float pa = sa, pb = sb;
    for (int off = 1; off < 64; off <<= 1) {
      const float oa = __shfl_up(pa, off, 64);
      const float ob = __shfl_up(pb, off, 64);
      if (lane >= off) { pa += oa; pb += ob; }
    }
    if (lane == 63) { wsumA[wv] = pa; wsumB[wv] = pb; }
    __syncthreads();
    float wpa = 0.f, wpb = 0.f;
    for (int w2 = 0; w2 < wv; ++w2) { wpa += wsumA[w2]; wpb += wsumB[w2]; }
    const float basea = wpa + pa - sa, baseb = wpb + pb - sb;
#pragma unroll
    for (int r = 0; r < 4; ++r) {
      sc1[base + 4 * t + r] = basea + a[r];
      sc2[base + 4 * t + r] = baseb + c[r];
    }
  } else {
#pragma unroll
    for (int r = 0; r < 4; ++r) {
      f2sort[base + 4 * t + r] = key2f((u32)(e[r] >> 32));
      jidxS[base + 4 * t + r]  = (int)(e[r] & 0xffffffffu);
    }
  }
}

// ---------------- Kernel 3b: alpha/beta per sorted-j, kpos per i ------------
__device__ __forceinline__ int lower_bound_s(const float* a, int n, float t) {
  int lo = 0, hi = n;
  while (lo < hi) {
    const int mid = (lo + hi) >> 1;
    if (a[mid] < t) lo = mid + 1; else hi = mid;
  }
  return lo;
}

__global__ __launch_bounds__(512) void k3b_ab(const float* __restrict__ f1sort,
                                              const float* __restrict__ sc1,
                                              const float* __restrict__ sc2,
                                              const float* __restrict__ f2sort,
                                              const float* __restrict__ f1g,
                                              float* __restrict__ alphaS,
                                              float* __restrict__ betaS,
                                              int* __restrict__ kposA) {
  __shared__ float s_f1[NN];  // 16 KiB
  __shared__ float s_f2[NN];  // 16 KiB
  const int b = blockIdx.x >> 3;
  const int part = blockIdx.x & 7;
  const int base = b * NN;
  for (int i = threadIdx.x; i < NN; i += 512) {
    s_f1[i] = f1sort[base + i];
    s_f2[i] = f2sort[base + i];
  }
  __syncthreads();
  const int g = part * 512 + threadIdx.x;
  const float T1 = sc1[base + NN - 1];
  const float f1max = s_f1[NN - 1];
  {
    const float f2v = s_f2[g];
    const float m = f1max + f2v;
    const float M = (m >= 0.f) ? m : SLOPE * m;      // column max of leaky scores
    const int p = lower_bound_s(s_f1, NN, -f2v);     // first i with f1 >= -f2
    const float S1 = T1 - (p > 0 ? sc1[base + p - 1] : 0.f);
    const float S2 = (p > 0 ? sc2[base + p - 1] : 0.f);
    const float ea = expf(f2v - M);
    const float eb = expf(SLOPE * f2v - M);
    const float invD = 1.0f / (ea * S1 + eb * S2);
    alphaS[base + g] = ea * invD;
    betaS[base + g]  = eb * invD;
  }
  {
    const float f1v = f1g[base + g];
    kposA[base + g] = lower_bound_s(s_f2, NN, -f1v); // first sorted-j with f2 >= -f1
  }
}

// ---------------- Kernel 4a: per-chunk partial sums -------------------------
__global__ __launch_bounds__(128) void k4a_csum(const float* __restrict__ feats,
                                                const float* __restrict__ alphaS,
                                                const float* __restrict__ betaS,
                                                const int* __restrict__ jidxS,
                                                float* __restrict__ csumA,
                                                float* __restrict__ csumB) {
  const int b = blockIdx.x / NCH, c = blockIdx.x % NCH;
  const int o = threadIdx.x;
  const int base = b * NN + c * CH;
  const float* fb = feats + (size_t)b * NN * FO;
  float accA = 0.f, accB = 0.f;
#pragma unroll 4
  for (int q = 0; q < CH; ++q) {
    const int kk = base + q;
    const int j = jidxS[kk];
    const float fv = fb[(size_t)j * FO + o];
    accA = fmaf(alphaS[kk], fv, accA);
    accB = fmaf(betaS[kk], fv, accB);
  }
  csumA[(size_t)(b * NCH + c) * FO + o] = accA;
  csumB[(size_t)(b * NCH + c) * FO + o] = accB;
}

// ---------------- Kernel 4b: exclusive prefix arrays ------------------------
__global__ __launch_bounds__(128) void k4b_prefix(const float* __restrict__ feats,
                                                  const float* __restrict__ alphaS,
                                                  const float* __restrict__ betaS,
                                                  const int* __restrict__ jidxS,
                                                  const float* __restrict__ csumA,
                                                  const float* __restrict__ csumB,
                                                  float* __restrict__ prefA,
                                                  float* __restrict__ prefB) {
  const int b = blockIdx.x / NCH, c = blockIdx.x % NCH;
  const int o = threadIdx.x;
  float runA = 0.f, runB = 0.f;
  for (int c2 = 0; c2 < c; ++c2) {
    runA += csumA[(size_t)(b * NCH + c2) * FO + o];
    runB += csumB[(size_t)(b * NCH + c2) * FO + o];
  }
  const int base = b * NN + c * CH;
  const float* fb = feats + (size_t)b * NN * FO;
  float* pA = prefA + (size_t)(b * (NN + 1) + c * CH) * FO + o;
  float* pB = prefB + (size_t)(b * (NN + 1) + c * CH) * FO + o;
  for (int q = 0; q < CH; ++q) {
    pA[q * FO] = runA;
    pB[q * FO] = runB;
    const int kk = base + q;
    const int j = jidxS[kk];
    const float fv = fb[(size_t)j * FO + o];
    runA = fmaf(alphaS[kk], fv, runA);
    runB = fmaf(betaS[kk], fv, runB);
  }
  if (c == NCH - 1) {
    prefA[(size_t)(b * (NN + 1) + NN) * FO + o] = runA;
    prefB[(size_t)(b * (NN + 1) + NN) * FO + o] = runB;
  }
}

// ---------------- Kernel 5: epilogue combine (f32 out) ----------------------
__global__ __launch_bounds__(256) void k5_out(const float* __restrict__ prefA,
                                              const float* __restrict__ prefB,
                                              const int* __restrict__ kposA,
                                              const float* __restrict__ E1g,
                                              const float* __restrict__ E2g,
                                              float* __restrict__ out) {
  const int t = threadIdx.x;
  const int row = blockIdx.x * 2 + (t >> 7);
  const int o = t & 127;
  const int b = row >> 12;  // NN = 4096
  const int kp = kposA[row];
  const float e1 = E1g[row], e2 = E2g[row];
  const float* pAb = prefA + (size_t)(b * (NN + 1)) * FO;
  const float* pBb = prefB + (size_t)(b * (NN + 1)) * FO;
  const float totA = pAb[(size_t)NN * FO + o];
  const float pA = pAb[(size_t)kp * FO + o];
  const float pB = pBb[(size_t)kp * FO + o];
  out[(size_t)row * FO + o] = fmaf(e1, totA - pA, e2 * pB);
}

extern "C" void kernel_launch(void* const* d_in, const int* in_sizes, int n_in,
                              void* d_out, int out_size, void* d_ws, size_t ws_size,
                              hipStream_t stream) {
  const float* x  = (const float*)d_in[0];
  const float* W  = (const float*)d_in[1];
  const float* wl = (const float*)d_in[2];
  const float* bl = (const float*)d_in[3];
  const float* wr = (const float*)d_in[4];
  const float* br = (const float*)d_in[5];
  float* out = (float*)d_out;

  float* ws = (float*)d_ws;
  float* feats  = ws; ws += NB * NN * FO;
  float* f1g    = ws; ws += NB * NN;
  float* f2g    = ws; ws += NB * NN;
  float* f1sort = ws; ws += NB * NN;
  float* f2sort = ws; ws += NB * NN;
  float* sc1    = ws; ws += NB * NN;
  float* sc2    = ws; ws += NB * NN;
  float* alphaS = ws; ws += NB * NN;
  float* betaS  = ws; ws += NB * NN;
  float* E1g    = ws; ws += NB * NN;
  float* E2g    = ws; ws += NB * NN;
  int* jidxS    = (int*)ws; ws += NB * NN;
  int* kposA    = (int*)ws; ws += NB * NN;
  float* csumA  = ws; ws += NB * NCH * FO;
  float* csumB  = ws; ws += NB * NCH * FO;
  float* prefA  = ws; ws += NB * (NN + 1) * FO;
  float* prefB  = ws; ws += NB * (NN + 1) * FO;
  (void)in_sizes; (void)n_in; (void)out_size; (void)ws_size;

  hipLaunchKernelGGL(k1_gemm,   dim3(NB * NN / 32), dim3(256),  0, stream,
                     x, W, wl, bl, wr, br, feats, f1g, f2g, E1g, E2g);
  hipLaunchKernelGGL(k3a_sort,  dim3(8),            dim3(1024), 0, stream,
                     f1g, f2g, f1sort, sc1, sc2, f2sort, jidxS);
  hipLaunchKernelGGL(k3b_ab,    dim3(NB * 8),       dim3(512),  0, stream,
                     f1sort, sc1, sc2, f2sort, f1g, alphaS, betaS, kposA);
  hipLaunchKernelGGL(k4a_csum,  dim3(NB * NCH),     dim3(128),  0, stream,
                     feats, alphaS, betaS, jidxS, csumA, csumB);
  hipLaunchKernelGGL(k4b_prefix,dim3(NB * NCH),     dim3(128),  0, stream,
                     feats, alphaS, betaS, jidxS, csumA, csumB, prefA, prefB);
  hipLaunchKernelGGL(k5_out,    dim3(NB * NN / 2),  dim3(256),  0, stream,
                     prefA, prefB, kposA, E1g, E2g, out);
}